// Round 1
// 212.999 us; speedup vs baseline: 1.0200x; 1.0200x over previous
//
#include <hip/hip_runtime.h>
#include <math.h>

typedef _Float16 half8_t __attribute__((ext_vector_type(8)));
typedef _Float16 half4_t __attribute__((ext_vector_type(4)));
typedef float f32x4 __attribute__((ext_vector_type(4)));

#define MFMA16(a, b, c) __builtin_amdgcn_mfma_f32_16x16x32_f16((a), (b), (c), 0, 0, 0)

// log2(e) / sqrt(128): fold softmax scale AND exp->exp2 conversion into q.
#define SCALE_Q (0.08838834764831845f * 1.44269504088896340736f)

// ---------------------------------------------------------------------------
// Kernel 0: W [512][128] fp32  ->  Wt [128][512] fp16   (x3 for q,k,v)
// ---------------------------------------------------------------------------
__global__ __launch_bounds__(256) void wt_kernel(const float* __restrict__ Wq,
                                                 const float* __restrict__ Wk,
                                                 const float* __restrict__ Wv,
                                                 _Float16* __restrict__ WtAll) {
    int y = blockIdx.y;
    const float* W = (y == 0) ? Wq : (y == 1) ? Wk : Wv;
    int idx = blockIdx.x * 256 + threadIdx.x;   // 0..65535, coalesced read
    int kk = idx >> 7;                           // d_in   0..511
    int d  = idx & 127;                          // d_att  0..127
    WtAll[y * 65536 + d * 512 + kk] = (_Float16)W[idx];
}

// ---------------------------------------------------------------------------
// Kernel 1: projection GEMM.  C[16384][128] = X[16384][512] @ W + b
// Double-buffered LDS, one barrier per K-step; next-tile global loads issued
// before the MFMA cluster so HBM latency hides under compute (T14).
// ---------------------------------------------------------------------------
__global__ __launch_bounds__(256) void proj_kernel(
    const float* __restrict__ q_in, const float* __restrict__ k_in,
    const float* __restrict__ v_in, const _Float16* __restrict__ WtAll,
    const float* __restrict__ biasq, const float* __restrict__ biask,
    const float* __restrict__ biasv,
    _Float16* __restrict__ qbuf, _Float16* __restrict__ kbuf,
    _Float16* __restrict__ vtbuf) {
    int y = blockIdx.y;
    const float* x = (y == 0) ? q_in : (y == 1) ? k_in : v_in;
    const _Float16* Wt = WtAll + y * 65536;
    const float* bias = (y == 0) ? biasq : (y == 1) ? biask : biasv;
    int row0 = blockIdx.x * 128;

    __shared__ _Float16 smem[20480];   // 40 KB; staging overlaid w/ epilogue
    _Float16* AsA = smem;              // [128][40]  (BK=32 +8 pad) current
    _Float16* WsA = smem + 5120;       // [128][40]
    _Float16* AsB = smem + 10240;      // next
    _Float16* WsB = smem + 15360;

    int tid = threadIdx.x;
    int wave = tid >> 6, lane = tid & 63, quad = lane >> 4, l16 = lane & 15;
    int wm = (wave & 1) * 64, wn = (wave >> 1) * 64;
    int arow = tid >> 1, acol = (tid & 1) * 16;

    f32x4 acc[4][4] = {};

    // prologue: stage K-block 0 into buffer A
    {
        const float4* ap = (const float4*)(x + (size_t)(row0 + arow) * 512 + acol);
        float4 a0 = ap[0], a1 = ap[1], a2 = ap[2], a3 = ap[3];
        const half8_t* wp = (const half8_t*)(Wt + arow * 512 + acol);
        half8_t w0 = wp[0], w1 = wp[1];
        half8_t h0, h1;
        h0[0] = (_Float16)a0.x; h0[1] = (_Float16)a0.y;
        h0[2] = (_Float16)a0.z; h0[3] = (_Float16)a0.w;
        h0[4] = (_Float16)a1.x; h0[5] = (_Float16)a1.y;
        h0[6] = (_Float16)a1.z; h0[7] = (_Float16)a1.w;
        h1[0] = (_Float16)a2.x; h1[1] = (_Float16)a2.y;
        h1[2] = (_Float16)a2.z; h1[3] = (_Float16)a2.w;
        h1[4] = (_Float16)a3.x; h1[5] = (_Float16)a3.y;
        h1[6] = (_Float16)a3.z; h1[7] = (_Float16)a3.w;
        *(half8_t*)&AsA[arow * 40 + acol]     = h0;
        *(half8_t*)&AsA[arow * 40 + acol + 8] = h1;
        *(half8_t*)&WsA[arow * 40 + acol]     = w0;
        *(half8_t*)&WsA[arow * 40 + acol + 8] = w1;
    }
    __syncthreads();

    for (int kb = 0; kb < 512; kb += 32) {
        bool more = (kb + 32) < 512;
        float4 a0, a1, a2, a3;
        half8_t w0, w1;
        if (more) {   // issue next-tile loads BEFORE compute; latency hides
            const float4* ap =
                (const float4*)(x + (size_t)(row0 + arow) * 512 + kb + 32 + acol);
            a0 = ap[0]; a1 = ap[1]; a2 = ap[2]; a3 = ap[3];
            const half8_t* wp = (const half8_t*)(Wt + arow * 512 + kb + 32 + acol);
            w0 = wp[0]; w1 = wp[1];
        }

        half8_t af[4], bf[4];
        for (int mt = 0; mt < 4; mt++)
            af[mt] = *(const half8_t*)&AsA[(wm + mt * 16 + l16) * 40 + quad * 8];
        for (int nt = 0; nt < 4; nt++)
            bf[nt] = *(const half8_t*)&WsA[(wn + nt * 16 + l16) * 40 + quad * 8];
        for (int mt = 0; mt < 4; mt++)
            for (int nt = 0; nt < 4; nt++)
                acc[mt][nt] = MFMA16(af[mt], bf[nt], acc[mt][nt]);

        if (more) {   // convert + write into the other buffer
            half8_t h0, h1;
            h0[0] = (_Float16)a0.x; h0[1] = (_Float16)a0.y;
            h0[2] = (_Float16)a0.z; h0[3] = (_Float16)a0.w;
            h0[4] = (_Float16)a1.x; h0[5] = (_Float16)a1.y;
            h0[6] = (_Float16)a1.z; h0[7] = (_Float16)a1.w;
            h1[0] = (_Float16)a2.x; h1[1] = (_Float16)a2.y;
            h1[2] = (_Float16)a2.z; h1[3] = (_Float16)a2.w;
            h1[4] = (_Float16)a3.x; h1[5] = (_Float16)a3.y;
            h1[6] = (_Float16)a3.z; h1[7] = (_Float16)a3.w;
            *(half8_t*)&AsB[arow * 40 + acol]     = h0;
            *(half8_t*)&AsB[arow * 40 + acol + 8] = h1;
            *(half8_t*)&WsB[arow * 40 + acol]     = w0;
            *(half8_t*)&WsB[arow * 40 + acol + 8] = w1;
        }
        __syncthreads();
        _Float16* tp;
        tp = AsA; AsA = AsB; AsB = tp;
        tp = WsA; WsA = WsB; WsB = tp;
    }

    // Epilogue: bias + scale, assemble tile in LDS, coalesced store.
    float scale = (y == 0) ? SCALE_Q : 1.0f;
    if (y < 2) {
        // row-major [s][d] tile in smem[128][136]
        for (int mt = 0; mt < 4; mt++)
            for (int nt = 0; nt < 4; nt++) {
                int d = wn + nt * 16 + l16;
                float b = bias[d];
                for (int r = 0; r < 4; r++)
                    smem[(wm + mt * 16 + quad * 4 + r) * 136 + d] =
                        (_Float16)((acc[mt][nt][r] + b) * scale);
            }
    } else {
        // transposed [d][s] tile in smem[128][136]
        for (int mt = 0; mt < 4; mt++)
            for (int nt = 0; nt < 4; nt++) {
                int d = wn + nt * 16 + l16;
                float b = bias[d];
                half4_t pk;
                for (int r = 0; r < 4; r++)
                    pk[r] = (_Float16)(acc[mt][nt][r] + b);
                *(half4_t*)&smem[d * 136 + wm + mt * 16 + quad * 4] = pk;
            }
    }
    __syncthreads();
    int srow = tid >> 1, scol = (tid & 1) * 64;
    if (y < 2) {
        _Float16* outp =
            ((y == 0) ? qbuf : kbuf) + (size_t)(row0 + srow) * 128 + scol;
        for (int i = 0; i < 8; i++)
            *(half8_t*)(outp + i * 8) =
                *(const half8_t*)&smem[srow * 136 + scol + i * 8];
    } else {
        int bbn = row0 >> 11, s0 = row0 & 2047;
        _Float16* outp =
            vtbuf + ((size_t)bbn * 128 + srow) * 2048 + s0 + scol;
        for (int i = 0; i < 8; i++)
            *(half8_t*)(outp + i * 8) =
                *(const half8_t*)&smem[srow * 136 + scol + i * 8];
    }
}

// ---------------------------------------------------------------------------
// Kernel 2: flash attention.  1 block = 64 q rows (4 waves x 16 q).
// Double-buffered K/V tiles, ONE barrier per tile; next tile's global loads
// issued before compute (T14); setprio around MFMA clusters (T5).
// Q fragments loaded straight from global (L2-resident), no Q stage.
// ---------------------------------------------------------------------------
__global__ __launch_bounds__(256) void attn_kernel(
    const _Float16* __restrict__ qbuf, const _Float16* __restrict__ kbuf,
    const _Float16* __restrict__ vtbuf, float* __restrict__ out) {
    int bb = blockIdx.x >> 5;
    int q0 = (blockIdx.x & 31) * 64;
    int tid = threadIdx.x, wave = tid >> 6, lane = tid & 63;
    int quad = lane >> 4, l16 = lane & 15;

    __shared__ _Float16 smem[40448];     // 80.9 KB
    _Float16* KsA = smem;                // [64][136]   (BKV=64 keys) current
    _Float16* KsB = smem + 8704;         // next
    _Float16* VsA = smem + 17408;        // [128][72]   (V^T: [d][key]) current
    _Float16* VsB = smem + 26624;        // next
    _Float16* Pt  = smem + 35840 + wave * 1152;   // [16][72] per wave

    // Q fragments straight from global: row (q0 + wave*16 + l16), col kc*32+quad*8
    half8_t qf[4];
    {
        const _Float16* qrow =
            qbuf + ((size_t)bb * 2048 + q0 + wave * 16 + l16) * 128 + quad * 8;
        qf[0] = *(const half8_t*)(qrow);
        qf[1] = *(const half8_t*)(qrow + 32);
        qf[2] = *(const half8_t*)(qrow + 64);
        qf[3] = *(const half8_t*)(qrow + 96);
    }

    const _Float16* kbase = kbuf + (size_t)bb * 2048 * 128;
    const _Float16* vbase = vtbuf + (size_t)bb * 128 * 2048;

    int krow = tid >> 2, kcol = (tid & 3) * 32;   // K stage: 64 x 128
    int vrow = tid >> 1, vcol = (tid & 1) * 32;   // V stage: 128 x 64

    // prologue: stage tile 0 into buffer A
    {
        const half8_t* ksrc =
            (const half8_t*)(kbase + (size_t)krow * 128 + kcol);
        half8_t k0 = ksrc[0], k1 = ksrc[1], k2 = ksrc[2], k3 = ksrc[3];
        const half8_t* vsrc =
            (const half8_t*)(vbase + (size_t)vrow * 2048 + vcol);
        half8_t x0 = vsrc[0], x1 = vsrc[1], x2 = vsrc[2], x3 = vsrc[3];
        *(half8_t*)&KsA[krow * 136 + kcol]      = k0;
        *(half8_t*)&KsA[krow * 136 + kcol + 8]  = k1;
        *(half8_t*)&KsA[krow * 136 + kcol + 16] = k2;
        *(half8_t*)&KsA[krow * 136 + kcol + 24] = k3;
        *(half8_t*)&VsA[vrow * 72 + vcol]       = x0;
        *(half8_t*)&VsA[vrow * 72 + vcol + 8]   = x1;
        *(half8_t*)&VsA[vrow * 72 + vcol + 16]  = x2;
        *(half8_t*)&VsA[vrow * 72 + vcol + 24]  = x3;
    }
    __syncthreads();

    f32x4 o[8] = {};
    float m = -INFINITY, l = 0.0f;

    for (int kv = 0; kv < 2048; kv += 64) {
        bool more = (kv + 64) < 2048;
        half8_t nk0, nk1, nk2, nk3, nx0, nx1, nx2, nx3;
        if (more) {   // issue next-tile loads; latency hides under compute
            const half8_t* ksrc =
                (const half8_t*)(kbase + (size_t)(kv + 64 + krow) * 128 + kcol);
            nk0 = ksrc[0]; nk1 = ksrc[1]; nk2 = ksrc[2]; nk3 = ksrc[3];
            const half8_t* vsrc =
                (const half8_t*)(vbase + (size_t)vrow * 2048 + kv + 64 + vcol);
            nx0 = vsrc[0]; nx1 = vsrc[1]; nx2 = vsrc[2]; nx3 = vsrc[3];
        }

        // S^T[key][q] = K Q^T   (4 key-subtiles x 16)
        f32x4 sf[4];
        __builtin_amdgcn_s_setprio(1);
        for (int kt = 0; kt < 4; kt++) {
            f32x4 a = {0.f, 0.f, 0.f, 0.f};
            for (int kc = 0; kc < 4; kc++) {
                half8_t kf = *(const half8_t*)&KsA[(kt * 16 + l16) * 136 +
                                                   kc * 32 + quad * 8];
                a = MFMA16(kf, qf[kc], a);
            }
            sf[kt] = a;
        }
        __builtin_amdgcn_s_setprio(0);

        // online softmax over this tile's 64 keys (per q = l16)
        float mx = -INFINITY;
        for (int kt = 0; kt < 4; kt++)
            for (int r = 0; r < 4; r++) mx = fmaxf(mx, sf[kt][r]);
        mx = fmaxf(mx, __shfl_xor(mx, 16, 64));
        mx = fmaxf(mx, __shfl_xor(mx, 32, 64));
        float mn = fmaxf(m, mx);
        float alpha = exp2f(m - mn);
        float rs = 0.0f;
        for (int kt = 0; kt < 4; kt++) {
            half4_t pk;
            for (int r = 0; r < 4; r++) {
                float p = exp2f(sf[kt][r] - mn);
                rs += p;
                pk[r] = (_Float16)p;
            }
            *(half4_t*)&Pt[l16 * 72 + kt * 16 + quad * 4] = pk;
        }
        rs += __shfl_xor(rs, 16, 64);
        rs += __shfl_xor(rs, 32, 64);
        l = l * alpha + rs;
        m = mn;

        // rescale O: alpha for row q' = quad*4+r lives at lane q'
        float ar0 = __shfl(alpha, quad * 4 + 0, 64);
        float ar1 = __shfl(alpha, quad * 4 + 1, 64);
        float ar2 = __shfl(alpha, quad * 4 + 2, 64);
        float ar3 = __shfl(alpha, quad * 4 + 3, 64);
        for (int t = 0; t < 8; t++) {
            o[t][0] *= ar0; o[t][1] *= ar1;
            o[t][2] *= ar2; o[t][3] *= ar3;
        }
        // O += P V
        half8_t pf0 = *(const half8_t*)&Pt[l16 * 72 + quad * 8];
        half8_t pf1 = *(const half8_t*)&Pt[l16 * 72 + 32 + quad * 8];
        __builtin_amdgcn_s_setprio(1);
        for (int t = 0; t < 8; t++) {
            half8_t v0 = *(const half8_t*)&VsA[(t * 16 + l16) * 72 + quad * 8];
            o[t] = MFMA16(pf0, v0, o[t]);
            half8_t v1 =
                *(const half8_t*)&VsA[(t * 16 + l16) * 72 + 32 + quad * 8];
            o[t] = MFMA16(pf1, v1, o[t]);
        }
        __builtin_amdgcn_s_setprio(0);

        if (more) {   // vmcnt-wait + write next tile into the other buffer
            *(half8_t*)&KsB[krow * 136 + kcol]      = nk0;
            *(half8_t*)&KsB[krow * 136 + kcol + 8]  = nk1;
            *(half8_t*)&KsB[krow * 136 + kcol + 16] = nk2;
            *(half8_t*)&KsB[krow * 136 + kcol + 24] = nk3;
            *(half8_t*)&VsB[vrow * 72 + vcol]       = nx0;
            *(half8_t*)&VsB[vrow * 72 + vcol + 8]   = nx1;
            *(half8_t*)&VsB[vrow * 72 + vcol + 16]  = nx2;
            *(half8_t*)&VsB[vrow * 72 + vcol + 24]  = nx3;
        }
        __syncthreads();   // single barrier per tile
        _Float16* tmp;
        tmp = KsA; KsA = KsB; KsB = tmp;
        tmp = VsA; VsA = VsB; VsB = tmp;
    }

    float li0 = 1.0f / __shfl(l, quad * 4 + 0, 64);
    float li1 = 1.0f / __shfl(l, quad * 4 + 1, 64);
    float li2 = 1.0f / __shfl(l, quad * 4 + 2, 64);
    float li3 = 1.0f / __shfl(l, quad * 4 + 3, 64);
    size_t srow = (size_t)bb * 2048 + q0 + wave * 16 + quad * 4;
    for (int t = 0; t < 8; t++) {
        int d = t * 16 + l16;
        out[(srow + 0) * 128 + d] = o[t][0] * li0;
        out[(srow + 1) * 128 + d] = o[t][1] * li1;
        out[(srow + 2) * 128 + d] = o[t][2] * li2;
        out[(srow + 3) * 128 + d] = o[t][3] * li3;
    }
}

// ---------------------------------------------------------------------------
extern "C" void kernel_launch(void* const* d_in, const int* in_sizes, int n_in,
                              void* d_out, int out_size, void* d_ws,
                              size_t ws_size, hipStream_t stream) {
    const float* q_in = (const float*)d_in[0];
    const float* k_in = (const float*)d_in[1];
    const float* v_in = (const float*)d_in[2];
    const float* Wq = (const float*)d_in[3];
    const float* Wk = (const float*)d_in[4];
    const float* Wv = (const float*)d_in[5];
    const float* bq = (const float*)d_in[6];
    const float* bk = (const float*)d_in[7];
    const float* bv = (const float*)d_in[8];
    float* out = (float*)d_out;

    char* ws = (char*)d_ws;
    _Float16* WtAll = (_Float16*)ws;                    // 3 * 65536 * 2 B
    _Float16* qbuf  = (_Float16*)(ws + 393216);         // 16384*128*2 = 4 MB
    _Float16* kbuf  = (_Float16*)(ws + 4587520);        // 4 MB
    _Float16* vtbuf = (_Float16*)(ws + 8781824);        // 4 MB (transposed)

    wt_kernel<<<dim3(256, 3), 256, 0, stream>>>(Wq, Wk, Wv, WtAll);
    proj_kernel<<<dim3(128, 3), 256, 0, stream>>>(q_in, k_in, v_in, WtAll, bq,
                                                  bk, bv, qbuf, kbuf, vtbuf);
    attn_kernel<<<dim3(256), 256, 0, stream>>>(qbuf, kbuf, vtbuf, out);
}

// Round 2
// 187.748 us; speedup vs baseline: 1.1572x; 1.1345x over previous
//
#include <hip/hip_runtime.h>
#include <math.h>

typedef _Float16 half8_t __attribute__((ext_vector_type(8)));
typedef _Float16 half4_t __attribute__((ext_vector_type(4)));
typedef float f32x4 __attribute__((ext_vector_type(4)));

#define MFMA16(a, b, c) __builtin_amdgcn_mfma_f32_16x16x32_f16((a), (b), (c), 0, 0, 0)

// log2(e) / sqrt(128): fold softmax scale AND exp->exp2 conversion into q.
#define SCALE_Q (0.08838834764831845f * 1.44269504088896340736f)

// ---------------------------------------------------------------------------
// Kernel 0: W [512][128] fp32  ->  Wt [128][512] fp16   (x3 for q,k,v)
// ---------------------------------------------------------------------------
__global__ __launch_bounds__(256) void wt_kernel(const float* __restrict__ Wq,
                                                 const float* __restrict__ Wk,
                                                 const float* __restrict__ Wv,
                                                 _Float16* __restrict__ WtAll) {
    int y = blockIdx.y;
    const float* W = (y == 0) ? Wq : (y == 1) ? Wk : Wv;
    int idx = blockIdx.x * 256 + threadIdx.x;   // 0..65535, coalesced read
    int kk = idx >> 7;                           // d_in   0..511
    int d  = idx & 127;                          // d_att  0..127
    WtAll[y * 65536 + d * 512 + kk] = (_Float16)W[idx];
}

// ---------------------------------------------------------------------------
// Kernel 1: projection GEMM.  C[16384][128] = X[16384][512] @ W + b
// Double-buffered LDS, one barrier per K-step; next-tile global loads issued
// before the MFMA cluster so HBM latency hides under compute (T14).
// ---------------------------------------------------------------------------
__global__ __launch_bounds__(256) void proj_kernel(
    const float* __restrict__ q_in, const float* __restrict__ k_in,
    const float* __restrict__ v_in, const _Float16* __restrict__ WtAll,
    const float* __restrict__ biasq, const float* __restrict__ biask,
    const float* __restrict__ biasv,
    _Float16* __restrict__ qbuf, _Float16* __restrict__ kbuf,
    _Float16* __restrict__ vtbuf) {
    int y = blockIdx.y;
    const float* x = (y == 0) ? q_in : (y == 1) ? k_in : v_in;
    const _Float16* Wt = WtAll + y * 65536;
    const float* bias = (y == 0) ? biasq : (y == 1) ? biask : biasv;
    int row0 = blockIdx.x * 128;

    __shared__ _Float16 smem[20480];   // 40 KB; staging overlaid w/ epilogue
    _Float16* AsA = smem;              // [128][40]  (BK=32 +8 pad) current
    _Float16* WsA = smem + 5120;       // [128][40]
    _Float16* AsB = smem + 10240;      // next
    _Float16* WsB = smem + 15360;

    int tid = threadIdx.x;
    int wave = tid >> 6, lane = tid & 63, quad = lane >> 4, l16 = lane & 15;
    int wm = (wave & 1) * 64, wn = (wave >> 1) * 64;
    int arow = tid >> 1, acol = (tid & 1) * 16;

    f32x4 acc[4][4] = {};

    // prologue: stage K-block 0 into buffer A
    {
        const float4* ap = (const float4*)(x + (size_t)(row0 + arow) * 512 + acol);
        float4 a0 = ap[0], a1 = ap[1], a2 = ap[2], a3 = ap[3];
        const half8_t* wp = (const half8_t*)(Wt + arow * 512 + acol);
        half8_t w0 = wp[0], w1 = wp[1];
        half8_t h0, h1;
        h0[0] = (_Float16)a0.x; h0[1] = (_Float16)a0.y;
        h0[2] = (_Float16)a0.z; h0[3] = (_Float16)a0.w;
        h0[4] = (_Float16)a1.x; h0[5] = (_Float16)a1.y;
        h0[6] = (_Float16)a1.z; h0[7] = (_Float16)a1.w;
        h1[0] = (_Float16)a2.x; h1[1] = (_Float16)a2.y;
        h1[2] = (_Float16)a2.z; h1[3] = (_Float16)a2.w;
        h1[4] = (_Float16)a3.x; h1[5] = (_Float16)a3.y;
        h1[6] = (_Float16)a3.z; h1[7] = (_Float16)a3.w;
        *(half8_t*)&AsA[arow * 40 + acol]     = h0;
        *(half8_t*)&AsA[arow * 40 + acol + 8] = h1;
        *(half8_t*)&WsA[arow * 40 + acol]     = w0;
        *(half8_t*)&WsA[arow * 40 + acol + 8] = w1;
    }
    __syncthreads();

    for (int kb = 0; kb < 512; kb += 32) {
        bool more = (kb + 32) < 512;
        float4 a0, a1, a2, a3;
        half8_t w0, w1;
        if (more) {   // issue next-tile loads BEFORE compute; latency hides
            const float4* ap =
                (const float4*)(x + (size_t)(row0 + arow) * 512 + kb + 32 + acol);
            a0 = ap[0]; a1 = ap[1]; a2 = ap[2]; a3 = ap[3];
            const half8_t* wp = (const half8_t*)(Wt + arow * 512 + kb + 32 + acol);
            w0 = wp[0]; w1 = wp[1];
        }

        half8_t af[4], bf[4];
        for (int mt = 0; mt < 4; mt++)
            af[mt] = *(const half8_t*)&AsA[(wm + mt * 16 + l16) * 40 + quad * 8];
        for (int nt = 0; nt < 4; nt++)
            bf[nt] = *(const half8_t*)&WsA[(wn + nt * 16 + l16) * 40 + quad * 8];
        for (int mt = 0; mt < 4; mt++)
            for (int nt = 0; nt < 4; nt++)
                acc[mt][nt] = MFMA16(af[mt], bf[nt], acc[mt][nt]);

        if (more) {   // convert + write into the other buffer
            half8_t h0, h1;
            h0[0] = (_Float16)a0.x; h0[1] = (_Float16)a0.y;
            h0[2] = (_Float16)a0.z; h0[3] = (_Float16)a0.w;
            h0[4] = (_Float16)a1.x; h0[5] = (_Float16)a1.y;
            h0[6] = (_Float16)a1.z; h0[7] = (_Float16)a1.w;
            h1[0] = (_Float16)a2.x; h1[1] = (_Float16)a2.y;
            h1[2] = (_Float16)a2.z; h1[3] = (_Float16)a2.w;
            h1[4] = (_Float16)a3.x; h1[5] = (_Float16)a3.y;
            h1[6] = (_Float16)a3.z; h1[7] = (_Float16)a3.w;
            *(half8_t*)&AsB[arow * 40 + acol]     = h0;
            *(half8_t*)&AsB[arow * 40 + acol + 8] = h1;
            *(half8_t*)&WsB[arow * 40 + acol]     = w0;
            *(half8_t*)&WsB[arow * 40 + acol + 8] = w1;
        }
        __syncthreads();
        _Float16* tp;
        tp = AsA; AsA = AsB; AsB = tp;
        tp = WsA; WsA = WsB; WsB = tp;
    }

    // Epilogue: bias + scale, assemble tile in LDS, coalesced store.
    float scale = (y == 0) ? SCALE_Q : 1.0f;
    if (y < 2) {
        // row-major [s][d] tile in smem[128][136]
        for (int mt = 0; mt < 4; mt++)
            for (int nt = 0; nt < 4; nt++) {
                int d = wn + nt * 16 + l16;
                float b = bias[d];
                for (int r = 0; r < 4; r++)
                    smem[(wm + mt * 16 + quad * 4 + r) * 136 + d] =
                        (_Float16)((acc[mt][nt][r] + b) * scale);
            }
    } else {
        // transposed [d][s] tile in smem[128][136]
        for (int mt = 0; mt < 4; mt++)
            for (int nt = 0; nt < 4; nt++) {
                int d = wn + nt * 16 + l16;
                float b = bias[d];
                half4_t pk;
                for (int r = 0; r < 4; r++)
                    pk[r] = (_Float16)(acc[mt][nt][r] + b);
                *(half4_t*)&smem[d * 136 + wm + mt * 16 + quad * 4] = pk;
            }
    }
    __syncthreads();
    int srow = tid >> 1, scol = (tid & 1) * 64;
    if (y < 2) {
        _Float16* outp =
            ((y == 0) ? qbuf : kbuf) + (size_t)(row0 + srow) * 128 + scol;
        for (int i = 0; i < 8; i++)
            *(half8_t*)(outp + i * 8) =
                *(const half8_t*)&smem[srow * 136 + scol + i * 8];
    } else {
        int bbn = row0 >> 11, s0 = row0 & 2047;
        _Float16* outp =
            vtbuf + ((size_t)bbn * 128 + srow) * 2048 + s0 + scol;
        for (int i = 0; i < 8; i++)
            *(half8_t*)(outp + i * 8) =
                *(const half8_t*)&smem[srow * 136 + scol + i * 8];
    }
}

// ---------------------------------------------------------------------------
// Kernel 2: flash attention.  1 block = 64 q rows, 8 waves (512 threads).
// Waves 0-3 process keys [0,1024); waves 4-7 keys [1024,2048) — 2 waves/SIMD
// so dependency-chain latency (MFMA, softmax fmax chain, shuffles, Pt LDS
// round-trip) is hidden by the co-resident wave. Each group has its own
// double-buffered K/V LDS (158 KB total). Partial (O,m,l) merged in LDS at
// the end (flash-decode style).
// ---------------------------------------------------------------------------
__global__ __launch_bounds__(512) void attn_kernel(
    const _Float16* __restrict__ qbuf, const _Float16* __restrict__ kbuf,
    const _Float16* __restrict__ vtbuf, float* __restrict__ out) {
    int bb = blockIdx.x >> 5;
    int q0 = (blockIdx.x & 31) * 64;
    int tid = threadIdx.x, wave = tid >> 6, lane = tid & 63;
    int group = wave >> 2, gw = wave & 3;
    int quad = lane >> 4, l16 = lane & 15;
    int tid_g = tid & 255;   // thread within KV-group

    __shared__ _Float16 smem[80896];   // 161792 B (fits 160 KiB CU budget)
    // layout (halfs): KsA0 0 | KsA1 8704 | VsA0 17408 | VsA1 26624 |
    //                 KsB0 35840 | KsB1 44544 | VsB0 53248 | VsB1 62464 |
    //                 Pt 71680 + wave*1152  (ends 80896)
    _Float16* KsA = smem + group * 8704;            // [64][136]
    _Float16* VsA = smem + 17408 + group * 9216;    // [128][72]
    _Float16* KsB = smem + 35840 + group * 8704;
    _Float16* VsB = smem + 53248 + group * 9216;
    _Float16* Pt  = smem + 71680 + wave * 1152;     // [16][72] per wave

    // Q fragments straight from global (L2-resident): 16 q rows per wave
    half8_t qf[4];
    {
        const _Float16* qrow =
            qbuf + ((size_t)bb * 2048 + q0 + gw * 16 + l16) * 128 + quad * 8;
        qf[0] = *(const half8_t*)(qrow);
        qf[1] = *(const half8_t*)(qrow + 32);
        qf[2] = *(const half8_t*)(qrow + 64);
        qf[3] = *(const half8_t*)(qrow + 96);
    }

    // per-group KV base: group g covers keys [g*1024, g*1024+1024)
    const _Float16* kbase = kbuf + ((size_t)bb * 2048 + group * 1024) * 128;
    const _Float16* vbase = vtbuf + (size_t)bb * 128 * 2048 + group * 1024;

    int krow = tid_g >> 2, kcol = (tid_g & 3) * 32;   // K stage: 64 x 128
    int vrow = tid_g >> 1, vcol = (tid_g & 1) * 32;   // V stage: 128 x 64

    // prologue: stage tile 0 into buffer A
    {
        const half8_t* ksrc =
            (const half8_t*)(kbase + (size_t)krow * 128 + kcol);
        half8_t k0 = ksrc[0], k1 = ksrc[1], k2 = ksrc[2], k3 = ksrc[3];
        const half8_t* vsrc =
            (const half8_t*)(vbase + (size_t)vrow * 2048 + vcol);
        half8_t x0 = vsrc[0], x1 = vsrc[1], x2 = vsrc[2], x3 = vsrc[3];
        *(half8_t*)&KsA[krow * 136 + kcol]      = k0;
        *(half8_t*)&KsA[krow * 136 + kcol + 8]  = k1;
        *(half8_t*)&KsA[krow * 136 + kcol + 16] = k2;
        *(half8_t*)&KsA[krow * 136 + kcol + 24] = k3;
        *(half8_t*)&VsA[vrow * 72 + vcol]       = x0;
        *(half8_t*)&VsA[vrow * 72 + vcol + 8]   = x1;
        *(half8_t*)&VsA[vrow * 72 + vcol + 16]  = x2;
        *(half8_t*)&VsA[vrow * 72 + vcol + 24]  = x3;
    }
    __syncthreads();

    f32x4 o[8] = {};
    float m = -INFINITY, l = 0.0f;

    for (int it = 0; it < 16; ++it) {
        int kv = it * 64;
        bool more = it < 15;
        half8_t nk0, nk1, nk2, nk3, nx0, nx1, nx2, nx3;
        if (more) {   // issue next-tile loads; latency hides under compute
            const half8_t* ksrc =
                (const half8_t*)(kbase + (size_t)(kv + 64 + krow) * 128 + kcol);
            nk0 = ksrc[0]; nk1 = ksrc[1]; nk2 = ksrc[2]; nk3 = ksrc[3];
            const half8_t* vsrc =
                (const half8_t*)(vbase + (size_t)vrow * 2048 + kv + 64 + vcol);
            nx0 = vsrc[0]; nx1 = vsrc[1]; nx2 = vsrc[2]; nx3 = vsrc[3];
        }

        // S^T[key][q] = K Q^T   (4 key-subtiles x 16)
        f32x4 sf[4];
        __builtin_amdgcn_s_setprio(1);
        for (int kt = 0; kt < 4; kt++) {
            f32x4 a = {0.f, 0.f, 0.f, 0.f};
            for (int kc = 0; kc < 4; kc++) {
                half8_t kf = *(const half8_t*)&KsA[(kt * 16 + l16) * 136 +
                                                   kc * 32 + quad * 8];
                a = MFMA16(kf, qf[kc], a);
            }
            sf[kt] = a;
        }
        __builtin_amdgcn_s_setprio(0);

        // online softmax over this tile's 64 keys (per q = l16)
        float mx = -INFINITY;
        for (int kt = 0; kt < 4; kt++)
            for (int r = 0; r < 4; r++) mx = fmaxf(mx, sf[kt][r]);
        mx = fmaxf(mx, __shfl_xor(mx, 16, 64));
        mx = fmaxf(mx, __shfl_xor(mx, 32, 64));
        float mn = fmaxf(m, mx);
        float alpha = exp2f(m - mn);
        float rs = 0.0f;
        for (int kt = 0; kt < 4; kt++) {
            half4_t pk;
            for (int r = 0; r < 4; r++) {
                float p = exp2f(sf[kt][r] - mn);
                rs += p;
                pk[r] = (_Float16)p;
            }
            *(half4_t*)&Pt[l16 * 72 + kt * 16 + quad * 4] = pk;
        }
        rs += __shfl_xor(rs, 16, 64);
        rs += __shfl_xor(rs, 32, 64);
        l = l * alpha + rs;
        m = mn;

        // rescale O: alpha for row q' = quad*4+r lives at lane q'
        float ar0 = __shfl(alpha, quad * 4 + 0, 64);
        float ar1 = __shfl(alpha, quad * 4 + 1, 64);
        float ar2 = __shfl(alpha, quad * 4 + 2, 64);
        float ar3 = __shfl(alpha, quad * 4 + 3, 64);
        for (int t = 0; t < 8; t++) {
            o[t][0] *= ar0; o[t][1] *= ar1;
            o[t][2] *= ar2; o[t][3] *= ar3;
        }
        // O += P V
        half8_t pf0 = *(const half8_t*)&Pt[l16 * 72 + quad * 8];
        half8_t pf1 = *(const half8_t*)&Pt[l16 * 72 + 32 + quad * 8];
        __builtin_amdgcn_s_setprio(1);
        for (int t = 0; t < 8; t++) {
            half8_t v0 = *(const half8_t*)&VsA[(t * 16 + l16) * 72 + quad * 8];
            o[t] = MFMA16(pf0, v0, o[t]);
            half8_t v1 =
                *(const half8_t*)&VsA[(t * 16 + l16) * 72 + 32 + quad * 8];
            o[t] = MFMA16(pf1, v1, o[t]);
        }
        __builtin_amdgcn_s_setprio(0);

        if (more) {   // write next tile into the other buffer
            *(half8_t*)&KsB[krow * 136 + kcol]      = nk0;
            *(half8_t*)&KsB[krow * 136 + kcol + 8]  = nk1;
            *(half8_t*)&KsB[krow * 136 + kcol + 16] = nk2;
            *(half8_t*)&KsB[krow * 136 + kcol + 24] = nk3;
            *(half8_t*)&VsB[vrow * 72 + vcol]       = nx0;
            *(half8_t*)&VsB[vrow * 72 + vcol + 8]   = nx1;
            *(half8_t*)&VsB[vrow * 72 + vcol + 16]  = nx2;
            *(half8_t*)&VsB[vrow * 72 + vcol + 24]  = nx3;
        }
        __syncthreads();   // single barrier per tile
        _Float16* tmp;
        tmp = KsA; KsA = KsB; KsB = tmp;
        tmp = VsA; VsA = VsB; VsB = tmp;
    }

    // -----------------------------------------------------------------------
    // Merge the two groups' partial (O, m, l) for the same 64 q rows.
    // Group1 writes raw partials to LDS (overlaying dead K/V staging);
    // group0 reads, merges, normalizes, stores.
    // -----------------------------------------------------------------------
    float* Of = (float*)smem;                 // [64][148] f32 (37888 B)
    float* Ml = (float*)(smem + 18944);       // [64][2]  f32

    if (group == 1) {
        int row = gw * 16 + quad * 4;
        for (int t = 0; t < 8; t++) {
            int d = t * 16 + l16;
            Of[(row + 0) * 148 + d] = o[t][0];
            Of[(row + 1) * 148 + d] = o[t][1];
            Of[(row + 2) * 148 + d] = o[t][2];
            Of[(row + 3) * 148 + d] = o[t][3];
        }
        if (quad == 0) {
            Ml[(gw * 16 + l16) * 2]     = m;
            Ml[(gw * 16 + l16) * 2 + 1] = l;
        }
    }
    __syncthreads();
    if (group == 0) {
        float m1 = Ml[(gw * 16 + l16) * 2];
        float l1 = Ml[(gw * 16 + l16) * 2 + 1];
        float mf = fmaxf(m, m1);
        float a0 = exp2f(m - mf), a1 = exp2f(m1 - mf);
        float lf = l * a0 + l1 * a1;
        float c0 = a0 / lf, c1 = a1 / lf;
        float c0r[4], c1r[4];
        for (int r = 0; r < 4; r++) {
            c0r[r] = __shfl(c0, quad * 4 + r, 64);
            c1r[r] = __shfl(c1, quad * 4 + r, 64);
        }
        int row = gw * 16 + quad * 4;
        size_t srow = (size_t)bb * 2048 + q0 + row;
        for (int t = 0; t < 8; t++) {
            int d = t * 16 + l16;
            for (int r = 0; r < 4; r++)
                out[(srow + r) * 128 + d] =
                    o[t][r] * c0r[r] + Of[(row + r) * 148 + d] * c1r[r];
        }
    }
}

// ---------------------------------------------------------------------------
extern "C" void kernel_launch(void* const* d_in, const int* in_sizes, int n_in,
                              void* d_out, int out_size, void* d_ws,
                              size_t ws_size, hipStream_t stream) {
    const float* q_in = (const float*)d_in[0];
    const float* k_in = (const float*)d_in[1];
    const float* v_in = (const float*)d_in[2];
    const float* Wq = (const float*)d_in[3];
    const float* Wk = (const float*)d_in[4];
    const float* Wv = (const float*)d_in[5];
    const float* bq = (const float*)d_in[6];
    const float* bk = (const float*)d_in[7];
    const float* bv = (const float*)d_in[8];
    float* out = (float*)d_out;

    char* ws = (char*)d_ws;
    _Float16* WtAll = (_Float16*)ws;                    // 3 * 65536 * 2 B
    _Float16* qbuf  = (_Float16*)(ws + 393216);         // 16384*128*2 = 4 MB
    _Float16* kbuf  = (_Float16*)(ws + 4587520);        // 4 MB
    _Float16* vtbuf = (_Float16*)(ws + 8781824);        // 4 MB (transposed)

    wt_kernel<<<dim3(256, 3), 256, 0, stream>>>(Wq, Wk, Wv, WtAll);
    proj_kernel<<<dim3(128, 3), 256, 0, stream>>>(q_in, k_in, v_in, WtAll, bq,
                                                  bk, bv, qbuf, kbuf, vtbuf);
    attn_kernel<<<dim3(256), 512, 0, stream>>>(qbuf, kbuf, vtbuf, out);
}

// Round 4
// 183.259 us; speedup vs baseline: 1.1855x; 1.0245x over previous
//
#include <hip/hip_runtime.h>
#include <math.h>

typedef _Float16 half8_t __attribute__((ext_vector_type(8)));
typedef _Float16 half4_t __attribute__((ext_vector_type(4)));
typedef _Float16 half2_t __attribute__((ext_vector_type(2)));
typedef float f32x4 __attribute__((ext_vector_type(4)));
typedef float f32x16 __attribute__((ext_vector_type(16)));
typedef unsigned int uint32x4 __attribute__((ext_vector_type(4)));

#define MFMA16(a, b, c) __builtin_amdgcn_mfma_f32_16x16x32_f16((a), (b), (c), 0, 0, 0)
#define MFMA32(a, b, c) __builtin_amdgcn_mfma_f32_32x32x16_f16((a), (b), (c), 0, 0, 0)

// log2(e) / sqrt(128): fold softmax scale AND exp->exp2 conversion into q.
#define SCALE_Q (0.08838834764831845f * 1.44269504088896340736f)

static __device__ inline unsigned int pkh(float a, float b) {
    half2_t h;
    h[0] = (_Float16)a;
    h[1] = (_Float16)b;
    return __builtin_bit_cast(unsigned int, h);
}

// ---------------------------------------------------------------------------
// Kernel 0: W [512][128] fp32  ->  Wt [128][512] fp16   (x3 for q,k,v)
// ---------------------------------------------------------------------------
__global__ __launch_bounds__(256) void wt_kernel(const float* __restrict__ Wq,
                                                 const float* __restrict__ Wk,
                                                 const float* __restrict__ Wv,
                                                 _Float16* __restrict__ WtAll) {
    int y = blockIdx.y;
    const float* W = (y == 0) ? Wq : (y == 1) ? Wk : Wv;
    int idx = blockIdx.x * 256 + threadIdx.x;
    int kk = idx >> 7;
    int d  = idx & 127;
    WtAll[y * 65536 + d * 512 + kk] = (_Float16)W[idx];
}

// ---------------------------------------------------------------------------
// Kernel 1: projection GEMM.  C[16384][128] = X[16384][512] @ W + b
// Double-buffered LDS, one barrier per K-step (T14 reg prefetch).
// ---------------------------------------------------------------------------
__global__ __launch_bounds__(256) void proj_kernel(
    const float* __restrict__ q_in, const float* __restrict__ k_in,
    const float* __restrict__ v_in, const _Float16* __restrict__ WtAll,
    const float* __restrict__ biasq, const float* __restrict__ biask,
    const float* __restrict__ biasv,
    _Float16* __restrict__ qbuf, _Float16* __restrict__ kbuf,
    _Float16* __restrict__ vtbuf) {
    int y = blockIdx.y;
    const float* x = (y == 0) ? q_in : (y == 1) ? k_in : v_in;
    const _Float16* Wt = WtAll + y * 65536;
    const float* bias = (y == 0) ? biasq : (y == 1) ? biask : biasv;
    int row0 = blockIdx.x * 128;

    __shared__ _Float16 smem[20480];
    _Float16* AsA = smem;
    _Float16* WsA = smem + 5120;
    _Float16* AsB = smem + 10240;
    _Float16* WsB = smem + 15360;

    int tid = threadIdx.x;
    int wave = tid >> 6, lane = tid & 63, quad = lane >> 4, l16 = lane & 15;
    int wm = (wave & 1) * 64, wn = (wave >> 1) * 64;
    int arow = tid >> 1, acol = (tid & 1) * 16;

    f32x4 acc[4][4] = {};

    {
        const float4* ap = (const float4*)(x + (size_t)(row0 + arow) * 512 + acol);
        float4 a0 = ap[0], a1 = ap[1], a2 = ap[2], a3 = ap[3];
        const half8_t* wp = (const half8_t*)(Wt + arow * 512 + acol);
        half8_t w0 = wp[0], w1 = wp[1];
        half8_t h0, h1;
        h0[0] = (_Float16)a0.x; h0[1] = (_Float16)a0.y;
        h0[2] = (_Float16)a0.z; h0[3] = (_Float16)a0.w;
        h0[4] = (_Float16)a1.x; h0[5] = (_Float16)a1.y;
        h0[6] = (_Float16)a1.z; h0[7] = (_Float16)a1.w;
        h1[0] = (_Float16)a2.x; h1[1] = (_Float16)a2.y;
        h1[2] = (_Float16)a2.z; h1[3] = (_Float16)a2.w;
        h1[4] = (_Float16)a3.x; h1[5] = (_Float16)a3.y;
        h1[6] = (_Float16)a3.z; h1[7] = (_Float16)a3.w;
        *(half8_t*)&AsA[arow * 40 + acol]     = h0;
        *(half8_t*)&AsA[arow * 40 + acol + 8] = h1;
        *(half8_t*)&WsA[arow * 40 + acol]     = w0;
        *(half8_t*)&WsA[arow * 40 + acol + 8] = w1;
    }
    __syncthreads();

    for (int kb = 0; kb < 512; kb += 32) {
        bool more = (kb + 32) < 512;
        float4 a0, a1, a2, a3;
        half8_t w0, w1;
        if (more) {
            const float4* ap =
                (const float4*)(x + (size_t)(row0 + arow) * 512 + kb + 32 + acol);
            a0 = ap[0]; a1 = ap[1]; a2 = ap[2]; a3 = ap[3];
            const half8_t* wp = (const half8_t*)(Wt + arow * 512 + kb + 32 + acol);
            w0 = wp[0]; w1 = wp[1];
        }

        half8_t af[4], bf[4];
        for (int mt = 0; mt < 4; mt++)
            af[mt] = *(const half8_t*)&AsA[(wm + mt * 16 + l16) * 40 + quad * 8];
        for (int nt = 0; nt < 4; nt++)
            bf[nt] = *(const half8_t*)&WsA[(wn + nt * 16 + l16) * 40 + quad * 8];
        for (int mt = 0; mt < 4; mt++)
            for (int nt = 0; nt < 4; nt++)
                acc[mt][nt] = MFMA16(af[mt], bf[nt], acc[mt][nt]);

        if (more) {
            half8_t h0, h1;
            h0[0] = (_Float16)a0.x; h0[1] = (_Float16)a0.y;
            h0[2] = (_Float16)a0.z; h0[3] = (_Float16)a0.w;
            h0[4] = (_Float16)a1.x; h0[5] = (_Float16)a1.y;
            h0[6] = (_Float16)a1.z; h0[7] = (_Float16)a1.w;
            h1[0] = (_Float16)a2.x; h1[1] = (_Float16)a2.y;
            h1[2] = (_Float16)a2.z; h1[3] = (_Float16)a2.w;
            h1[4] = (_Float16)a3.x; h1[5] = (_Float16)a3.y;
            h1[6] = (_Float16)a3.z; h1[7] = (_Float16)a3.w;
            *(half8_t*)&AsB[arow * 40 + acol]     = h0;
            *(half8_t*)&AsB[arow * 40 + acol + 8] = h1;
            *(half8_t*)&WsB[arow * 40 + acol]     = w0;
            *(half8_t*)&WsB[arow * 40 + acol + 8] = w1;
        }
        __syncthreads();
        _Float16* tp;
        tp = AsA; AsA = AsB; AsB = tp;
        tp = WsA; WsA = WsB; WsB = tp;
    }

    float scale = (y == 0) ? SCALE_Q : 1.0f;
    if (y < 2) {
        for (int mt = 0; mt < 4; mt++)
            for (int nt = 0; nt < 4; nt++) {
                int d = wn + nt * 16 + l16;
                float b = bias[d];
                for (int r = 0; r < 4; r++)
                    smem[(wm + mt * 16 + quad * 4 + r) * 136 + d] =
                        (_Float16)((acc[mt][nt][r] + b) * scale);
            }
    } else {
        for (int mt = 0; mt < 4; mt++)
            for (int nt = 0; nt < 4; nt++) {
                int d = wn + nt * 16 + l16;
                float b = bias[d];
                half4_t pk;
                for (int r = 0; r < 4; r++)
                    pk[r] = (_Float16)(acc[mt][nt][r] + b);
                *(half4_t*)&smem[d * 136 + wm + mt * 16 + quad * 4] = pk;
            }
    }
    __syncthreads();
    int srow = tid >> 1, scol = (tid & 1) * 64;
    if (y < 2) {
        _Float16* outp =
            ((y == 0) ? qbuf : kbuf) + (size_t)(row0 + srow) * 128 + scol;
        for (int i = 0; i < 8; i++)
            *(half8_t*)(outp + i * 8) =
                *(const half8_t*)&smem[srow * 136 + scol + i * 8];
    } else {
        int bbn = row0 >> 11, s0 = row0 & 2047;
        _Float16* outp =
            vtbuf + ((size_t)bbn * 128 + srow) * 2048 + s0 + scol;
        for (int i = 0; i < 8; i++)
            *(half8_t*)(outp + i * 8) =
                *(const half8_t*)&smem[srow * 136 + scol + i * 8];
    }
}

// ---------------------------------------------------------------------------
// Kernel 2: flash attention, 32x32 MFMA, in-register P (no Pt LDS).
// 1 block = 64 q rows, 8 waves: {g = kv-half} x {qsub = 32-q-subtile} x
// {kt = 32-key-subtile}. Swapped QK^T (S^T = K Q^T) puts q = lane&31 so the
// softmax max/sum folds with ONE shfl_xor(32); alpha & 1/l are lane-local.
// P -> PV B-operand via 4 shfl_xor(32) cross-hi exchange (T12 mechanism).
// O^T accumulated in regs; 4 partial (O,m,l) chains merged in LDS at end.
// ---------------------------------------------------------------------------
__global__ __launch_bounds__(512, 2) void attn_kernel(
    const _Float16* __restrict__ qbuf, const _Float16* __restrict__ kbuf,
    const _Float16* __restrict__ vtbuf, float* __restrict__ out) {
    int bb = blockIdx.x >> 5;
    int q0 = (blockIdx.x & 31) * 64;
    int tid = threadIdx.x, wave = tid >> 6, lane = tid & 63;
    int g = wave >> 2, qsub = (wave >> 1) & 1, kt = wave & 1;
    int l32 = lane & 31, hi = lane >> 5, hi8 = hi * 8;

    __shared__ _Float16 smem[71680];   // 143,360 B
    _Float16* KsA = smem + g * 35840;            // [64][136]
    _Float16* KsB = KsA + 8704;
    _Float16* VsA = smem + g * 35840 + 17408;    // [128][72]  (V^T: [d][key])
    _Float16* VsB = VsA + 9216;

    // Q fragments: B-frag for 32x32x16: B[k=hi*8+j][q=l32]
    half8_t qf[8];
    {
        const _Float16* qrow =
            qbuf + ((size_t)bb * 2048 + q0 + qsub * 32 + l32) * 128 + hi8;
#pragma unroll
        for (int kc = 0; kc < 8; kc++)
            qf[kc] = *(const half8_t*)(qrow + kc * 16);
    }

    const _Float16* kbase = kbuf + ((size_t)bb * 2048 + g * 1024) * 128;
    const _Float16* vbase = vtbuf + (size_t)bb * 128 * 2048 + g * 1024;

    int tg = tid & 255;                           // thread within kv-group
    int krow = tg >> 2, kcol = (tg & 3) * 32;     // K stage: 64 x 128
    int vrow = tg >> 1, vcol = (tg & 1) * 32;     // V stage: 128 x 64

    // prologue: stage tile 0 into buffer A
    {
        const half8_t* ks = (const half8_t*)(kbase + (size_t)krow * 128 + kcol);
        half8_t k0 = ks[0], k1 = ks[1], k2 = ks[2], k3 = ks[3];
        const half8_t* vs = (const half8_t*)(vbase + (size_t)vrow * 2048 + vcol);
        half8_t v0 = vs[0], v1 = vs[1], v2 = vs[2], v3 = vs[3];
        *(half8_t*)&KsA[krow * 136 + kcol]      = k0;
        *(half8_t*)&KsA[krow * 136 + kcol + 8]  = k1;
        *(half8_t*)&KsA[krow * 136 + kcol + 16] = k2;
        *(half8_t*)&KsA[krow * 136 + kcol + 24] = k3;
        *(half8_t*)&VsA[vrow * 72 + vcol]       = v0;
        *(half8_t*)&VsA[vrow * 72 + vcol + 8]   = v1;
        *(half8_t*)&VsA[vrow * 72 + vcol + 16]  = v2;
        *(half8_t*)&VsA[vrow * 72 + vcol + 24]  = v3;
    }
    __syncthreads();

    f32x16 acc0 = {}, acc1 = {}, acc2 = {}, acc3 = {};
    float m = -INFINITY, l = 0.0f;

    for (int it = 0; it < 16; ++it) {
        bool more = it < 15;
        half8_t nk0, nk1, nk2, nk3, nv0, nv1, nv2, nv3;
        if (more) {   // T14: issue next-tile loads before compute
            const half8_t* ks =
                (const half8_t*)(kbase + (size_t)((it + 1) * 64 + krow) * 128 + kcol);
            nk0 = ks[0]; nk1 = ks[1]; nk2 = ks[2]; nk3 = ks[3];
            const half8_t* vs =
                (const half8_t*)(vbase + (size_t)vrow * 2048 + (it + 1) * 64 + vcol);
            nv0 = vs[0]; nv1 = vs[1]; nv2 = vs[2]; nv3 = vs[3];
        }

        // S^T[key][q] = K Q^T for this wave's 32 keys (kt subtile)
        f32x16 sf = {};
        __builtin_amdgcn_s_setprio(1);
#pragma unroll
        for (int kc = 0; kc < 8; kc++) {
            half8_t kf =
                *(const half8_t*)&KsA[(kt * 32 + l32) * 136 + kc * 16 + hi8];
            sf = MFMA32(kf, qf[kc], sf);
        }
        __builtin_amdgcn_s_setprio(0);

        // online softmax; q = l32 per lane; keys split across hi halves
        float mx = sf[0];
#pragma unroll
        for (int i = 1; i < 16; i++) mx = fmaxf(mx, sf[i]);
        mx = fmaxf(mx, __shfl_xor(mx, 32, 64));
        if (!__all(mx <= m + 8.0f)) {   // T13 defer-max (THR=8)
            float mn = fmaxf(m, mx);
            float al = exp2f(m - mn);
            l *= al;
            acc0 *= al; acc1 *= al; acc2 *= al; acc3 *= al;
            m = mn;
        }
        float p[16];
        float rs = 0.0f;
#pragma unroll
        for (int i = 0; i < 16; i++) {
            p[i] = exp2f(sf[i] - m);
            rs += p[i];
        }
        rs += __shfl_xor(rs, 32, 64);
        l += rs;

        // pack P (key = (r&3)+8*(r>>2)+4*hi), cross-hi exchange -> B-frags
        unsigned int u0 = pkh(p[0], p[1]),   u1 = pkh(p[2], p[3]);
        unsigned int u2 = pkh(p[4], p[5]),   u3 = pkh(p[6], p[7]);
        unsigned int u4 = pkh(p[8], p[9]),   u5 = pkh(p[10], p[11]);
        unsigned int u6 = pkh(p[12], p[13]), u7 = pkh(p[14], p[15]);
        unsigned int x00 = hi ? u0 : u2, x01 = hi ? u1 : u3;
        unsigned int x10 = hi ? u4 : u6, x11 = hi ? u5 : u7;
        unsigned int r00 = __shfl_xor(x00, 32, 64), r01 = __shfl_xor(x01, 32, 64);
        unsigned int r10 = __shfl_xor(x10, 32, 64), r11 = __shfl_xor(x11, 32, 64);
        uint32x4 b0u, b1u;
        b0u[0] = hi ? r00 : u0; b0u[1] = hi ? r01 : u1;
        b0u[2] = hi ? u2 : r00; b0u[3] = hi ? u3 : r01;
        b1u[0] = hi ? r10 : u4; b1u[1] = hi ? r11 : u5;
        b1u[2] = hi ? u6 : r10; b1u[3] = hi ? u7 : r11;
        half8_t pb0 = __builtin_bit_cast(half8_t, b0u);
        half8_t pb1 = __builtin_bit_cast(half8_t, b1u);

        // O^T[d][q] += V^T P^T  (A = V^T rows d, B = P^T cols q)
        __builtin_amdgcn_s_setprio(1);
        {
            half8_t v0 = *(const half8_t*)&VsA[(0 * 32 + l32) * 72 + kt * 32 + hi8];
            acc0 = MFMA32(v0, pb0, acc0);
            half8_t v1 = *(const half8_t*)&VsA[(0 * 32 + l32) * 72 + kt * 32 + 16 + hi8];
            acc0 = MFMA32(v1, pb1, acc0);
            half8_t v2 = *(const half8_t*)&VsA[(1 * 32 + l32) * 72 + kt * 32 + hi8];
            acc1 = MFMA32(v2, pb0, acc1);
            half8_t v3 = *(const half8_t*)&VsA[(1 * 32 + l32) * 72 + kt * 32 + 16 + hi8];
            acc1 = MFMA32(v3, pb1, acc1);
            half8_t v4 = *(const half8_t*)&VsA[(2 * 32 + l32) * 72 + kt * 32 + hi8];
            acc2 = MFMA32(v4, pb0, acc2);
            half8_t v5 = *(const half8_t*)&VsA[(2 * 32 + l32) * 72 + kt * 32 + 16 + hi8];
            acc2 = MFMA32(v5, pb1, acc2);
            half8_t v6 = *(const half8_t*)&VsA[(3 * 32 + l32) * 72 + kt * 32 + hi8];
            acc3 = MFMA32(v6, pb0, acc3);
            half8_t v7 = *(const half8_t*)&VsA[(3 * 32 + l32) * 72 + kt * 32 + 16 + hi8];
            acc3 = MFMA32(v7, pb1, acc3);
        }
        __builtin_amdgcn_s_setprio(0);

        if (more) {
            *(half8_t*)&KsB[krow * 136 + kcol]      = nk0;
            *(half8_t*)&KsB[krow * 136 + kcol + 8]  = nk1;
            *(half8_t*)&KsB[krow * 136 + kcol + 16] = nk2;
            *(half8_t*)&KsB[krow * 136 + kcol + 24] = nk3;
            *(half8_t*)&VsB[vrow * 72 + vcol]       = nv0;
            *(half8_t*)&VsB[vrow * 72 + vcol + 8]   = nv1;
            *(half8_t*)&VsB[vrow * 72 + vcol + 16]  = nv2;
            *(half8_t*)&VsB[vrow * 72 + vcol + 24]  = nv3;
        }
        __syncthreads();
        _Float16* tmp;
        tmp = KsA; KsA = KsB; KsB = tmp;
        tmp = VsA; VsA = VsB; VsB = tmp;
    }

    // -----------------------------------------------------------------------
    // Merge the 4 partial chains (g,kt) per qsub. Tree: kt-pairs, then g-pairs.
    // Scratch overlays dead K/V LDS: R1[4 regions][128][33] f32 + ml[4][64].
    // -----------------------------------------------------------------------
    float* R1 = (float*)smem;
    const int RS = 33;
    int wid2 = g * 2 + qsub;
    float* Om = R1 + wid2 * (128 * RS);
    float* Ml = R1 + 4 * 128 * RS + wid2 * 64;

#define STORE_ACC(DST, A, DT)                                             \
    {                                                                     \
        _Pragma("unroll") for (int r = 0; r < 16; r++) {                  \
            int d = (r & 3) + 8 * (r >> 2) + 4 * hi + 32 * (DT);          \
            (DST)[d * RS + l32] = (A)[r];                                 \
        }                                                                 \
    }
#define MERGE_ACC(SRC, A, DT)                                             \
    {                                                                     \
        _Pragma("unroll") for (int r = 0; r < 16; r++) {                  \
            int d = (r & 3) + 8 * (r >> 2) + 4 * hi + 32 * (DT);          \
            (A)[r] = (A)[r] * sa + (SRC)[d * RS + l32] * sb;              \
        }                                                                 \
    }

    if (kt == 1) {
        STORE_ACC(Om, acc0, 0); STORE_ACC(Om, acc1, 1);
        STORE_ACC(Om, acc2, 2); STORE_ACC(Om, acc3, 3);
        if (hi == 0) { Ml[l32] = m; Ml[32 + l32] = l; }
    }
    __syncthreads();
    if (kt == 0) {
        float m1 = Ml[l32], l1 = Ml[32 + l32];
        float mf = fmaxf(m, m1);
        float sa = exp2f(m - mf), sb = exp2f(m1 - mf);
        l = l * sa + l1 * sb;
        m = mf;
        MERGE_ACC(Om, acc0, 0); MERGE_ACC(Om, acc1, 1);
        MERGE_ACC(Om, acc2, 2); MERGE_ACC(Om, acc3, 3);
    }
    __syncthreads();
    if (kt == 0 && g == 1) {
        float* Om2 = R1 + qsub * (128 * RS);
        float* Ml2 = R1 + 4 * 128 * RS + qsub * 64;
        STORE_ACC(Om2, acc0, 0); STORE_ACC(Om2, acc1, 1);
        STORE_ACC(Om2, acc2, 2); STORE_ACC(Om2, acc3, 3);
        if (hi == 0) { Ml2[l32] = m; Ml2[32 + l32] = l; }
    }
    __syncthreads();
    if (kt == 0 && g == 0) {
        float* Om2 = R1 + qsub * (128 * RS);
        float* Ml2 = R1 + 4 * 128 * RS + qsub * 64;
        float m1 = Ml2[l32], l1 = Ml2[32 + l32];
        float mf = fmaxf(m, m1);
        float sa = exp2f(m - mf), sb = exp2f(m1 - mf);
        float lf = l * sa + l1 * sb;
        float inv = 1.0f / lf;
        float* op = out + ((size_t)bb * 2048 + q0 + qsub * 32 + l32) * 128;
#define FINAL_ACC(A, DT)                                                  \
        {                                                                 \
            _Pragma("unroll") for (int r = 0; r < 16; r++) {              \
                int d = (r & 3) + 8 * (r >> 2) + 4 * hi + 32 * (DT);      \
                op[d] = ((A)[r] * sa + Om2[d * RS + l32] * sb) * inv;     \
            }                                                             \
        }
        FINAL_ACC(acc0, 0); FINAL_ACC(acc1, 1);
        FINAL_ACC(acc2, 2); FINAL_ACC(acc3, 3);
#undef FINAL_ACC
    }
#undef STORE_ACC
#undef MERGE_ACC
}

// ---------------------------------------------------------------------------
extern "C" void kernel_launch(void* const* d_in, const int* in_sizes, int n_in,
                              void* d_out, int out_size, void* d_ws,
                              size_t ws_size, hipStream_t stream) {
    const float* q_in = (const float*)d_in[0];
    const float* k_in = (const float*)d_in[1];
    const float* v_in = (const float*)d_in[2];
    const float* Wq = (const float*)d_in[3];
    const float* Wk = (const float*)d_in[4];
    const float* Wv = (const float*)d_in[5];
    const float* bq = (const float*)d_in[6];
    const float* bk = (const float*)d_in[7];
    const float* bv = (const float*)d_in[8];
    float* out = (float*)d_out;

    char* ws = (char*)d_ws;
    _Float16* WtAll = (_Float16*)ws;                    // 3 * 65536 * 2 B
    _Float16* qbuf  = (_Float16*)(ws + 393216);         // 16384*128*2 = 4 MB
    _Float16* kbuf  = (_Float16*)(ws + 4587520);        // 4 MB
    _Float16* vtbuf = (_Float16*)(ws + 8781824);        // 4 MB (transposed)

    wt_kernel<<<dim3(256, 3), 256, 0, stream>>>(Wq, Wk, Wv, WtAll);
    proj_kernel<<<dim3(128, 3), 256, 0, stream>>>(q_in, k_in, v_in, WtAll, bq,
                                                  bk, bv, qbuf, kbuf, vtbuf);
    attn_kernel<<<dim3(256), 512, 0, stream>>>(qbuf, kbuf, vtbuf, out);
}